// Round 1
// baseline (377.599 us; speedup 1.0000x reference)
//
#include <hip/hip_runtime.h>
#include <math.h>

// Problem constants
#define HH 100
#define WWd 352
#define HWSZ (HH*WWd)      // 35200
#define H4 25
#define W4 88
#define HW4 (H4*W4)        // 2200
#define Bb 4
#define Ll 5
#define Nn 20
#define Cc 64
#define Tt 10

// Fixed 5x5 gaussian (1/(2*pi*sigma) * exp(-(x^2+y^2)/(2 sigma^2)), sigma=1),
// computed in double then cast to float = numpy float64 -> float32 path.
__constant__ float G5[5][5] = {
    {(float)0.0029150244650281935, (float)0.0130642332846849210, (float)0.0215392793018486340, (float)0.0130642332846849210, (float)0.0029150244650281935},
    {(float)0.0130642332846849210, (float)0.0585498315243191680, (float)0.0965323526300539140, (float)0.0585498315243191680, (float)0.0130642332846849210},
    {(float)0.0215392793018486340, (float)0.0965323526300539140, (float)0.1591549430918953500, (float)0.0965323526300539140, (float)0.0215392793018486340},
    {(float)0.0130642332846849210, (float)0.0585498315243191680, (float)0.0965323526300539140, (float)0.0585498315243191680, (float)0.0130642332846849210},
    {(float)0.0029150244650281935, (float)0.0130642332846849210, (float)0.0215392793018486340, (float)0.0130642332846849210, (float)0.0029150244650281935},
};

// K1: per-trajectory mask at H4 x W4, plus has_traj flag.
// One block per n (20 blocks). Exploits: conv input is spatially constant ->
// attention map has only 9 distinct values (border categories).
__global__ __launch_bounds__(256) void k_trajmask(
    const float* __restrict__ traj,                  // [20,10,3]
    const float* __restrict__ W1, const float* __restrict__ b1,   // (3,64),(64)
    const float* __restrict__ W2, const float* __restrict__ b2,   // (64,128),(128)
    const float* __restrict__ Wc1, const float* __restrict__ bc1, // (64,128,3,3),(64)
    const float* __restrict__ Wc2, const float* __restrict__ bc2, // (64),(1)
    float* __restrict__ tm4,                          // [20,25,88]
    float* __restrict__ hastraj)                      // [20]
{
    __shared__ float tr[30];
    __shared__ int   xi[10], yi[10];
    __shared__ float hsum[64];
    __shared__ float fmean[128];
    __shared__ float S[576];      // [o=64][kh*3+kw=9]
    __shared__ float attCat[9];
    __shared__ float mmap[HW4];
    __shared__ float red[256];

    const int n = blockIdx.x, tid = threadIdx.x;
    if (tid < 30) tr[tid] = traj[n*30 + tid];
    __syncthreads();

    if (tid < 10) {
        // pts = traj[:, :2] / 0.4 ; idx = (pts/4).astype(int32) ; clip
        float px = (tr[tid*3+0] / 0.4f) / 4.0f;
        float py = (tr[tid*3+1] / 0.4f) / 4.0f;
        int x = (int)px; x = min(max(x, 0), W4-1);
        int y = (int)py; y = min(max(y, 0), H4-1);
        xi[tid] = x; yi[tid] = y;
    }
    if (tid == 0) {
        bool any = false;
        for (int i = 0; i < 30; i++) any = any || (tr[i] != 0.0f);
        hastraj[n] = any ? 1.0f : 0.0f;
    }
    if (tid < 64) {
        // hsum[j] = sum_t relu(traj[t] @ W1[:,j] + b1[j])
        float s = 0.f;
        for (int t = 0; t < 10; t++) {
            float h = tr[t*3+0]*W1[tid] + tr[t*3+1]*W1[64+tid] + tr[t*3+2]*W1[128+tid] + b1[tid];
            s += fmaxf(h, 0.f);
        }
        hsum[tid] = s;
    }
    __syncthreads();

    if (tid < 128) {
        // fmean[k] = mean_t f[t][k] = b2[k] + (sum_j hsum[j] W2[j][k]) / 10
        float s = 0.f;
        for (int j = 0; j < 64; j++) s += hsum[j]*W2[j*128 + tid];
        fmean[tid] = s/10.0f + b2[tid];
    }
    __syncthreads();

    for (int idx = tid; idx < 576; idx += 256) {
        int o = idx/9, kk = idx%9;
        const float* w = Wc1 + o*128*9 + kk;
        float s = 0.f;
        for (int ci = 0; ci < 128; ci++) s += w[ci*9]*fmean[ci];
        S[idx] = s;
    }
    __syncthreads();

    if (tid < 9) {
        // 9 border categories: which conv taps are in-bounds
        int ty = tid/3, tx = tid%3;
        int kh0 = (ty==0)?1:0, kh1 = (ty==2)?1:2;
        int kw0 = (tx==0)?1:0, kw1 = (tx==2)?1:2;
        float acc = bc2[0];
        for (int o = 0; o < 64; o++) {
            float s = bc1[o];
            for (int kh = kh0; kh <= kh1; kh++)
                for (int kw = kw0; kw <= kw1; kw++)
                    s += S[o*9 + kh*3 + kw];
            acc += Wc2[o]*fmaxf(s, 0.f);
        }
        attCat[tid] = 1.0f/(1.0f + expf(-acc));
    }

    // gaussian splat (7x7 window per point, sigma=2)
    float part = 0.f;
    for (int p = tid; p < HW4; p += 256) {
        int y = p/W4, x = p%W4;
        float m = 0.f;
        for (int t = 0; t < 10; t++) {
            int dy = y - yi[t], dx = x - xi[t];
            if (dy >= -3 && dy <= 3 && dx >= -3 && dx <= 3)
                m += expf(-(float)(dy*dy + dx*dx)*0.125f);
        }
        mmap[p] = m; part += m;
    }
    red[tid] = part;
    __syncthreads();
    for (int s = 128; s > 0; s >>= 1) {
        if (tid < s) red[tid] += red[tid+s];
        __syncthreads();
    }
    float norm = fmaxf(red[0], 1e-12f);

    for (int p = tid; p < HW4; p += 256) {
        int y = p/W4, x = p%W4;
        int ty = (y==0)?0:((y==H4-1)?2:1);
        int tx = (x==0)?0:((x==W4-1)?2:1);
        tm4[n*HW4 + p] = (mmap[p]/norm)*attCat[ty*3 + tx];
    }
}

// K2: smax[n,h,w] = sigmoid(max_a(psm[n,a,h,w] * (1 + has_traj*tm_up)))
__global__ __launch_bounds__(256) void k_smax(
    const float* __restrict__ psm, const float* __restrict__ tm4,
    const float* __restrict__ hastraj, float* __restrict__ smax)
{
    int p = blockIdx.x*256 + threadIdx.x;
    int n = blockIdx.y;
    if (p >= HWSZ) return;
    int h = p / WWd, w = p % WWd;

    // jax.image.resize 'bilinear' upsample x4: half-pixel centers, edge-normalized
    float fy = (h + 0.5f)*0.25f - 0.5f;
    float fx = (w + 0.5f)*0.25f - 0.5f;
    int y0 = (int)floorf(fy); float fry = fy - (float)y0;
    int x0 = (int)floorf(fx); float frx = fx - (float)x0;
    int ya = min(max(y0, 0), H4-1), yb = min(max(y0+1, 0), H4-1);
    int xa = min(max(x0, 0), W4-1), xb = min(max(x0+1, 0), W4-1);
    const float* tm = tm4 + n*HW4;
    float v00 = tm[ya*W4+xa], v01 = tm[ya*W4+xb];
    float v10 = tm[yb*W4+xa], v11 = tm[yb*W4+xb];
    float top = (1.f-frx)*v00 + frx*v01;
    float bot = (1.f-frx)*v10 + frx*v11;
    float tmv = (1.f-fry)*top + fry*bot;

    float fac = 1.0f + hastraj[n]*tmv;
    float a0 = psm[(size_t)(n*2+0)*HWSZ + p]*fac;
    float a1 = psm[(size_t)(n*2+1)*HWSZ + p]*fac;
    float mx = fmaxf(a0, a1);   // max(sigmoid(a),sigmoid(b)) = sigmoid(max(a,b))
    smax[(size_t)n*HWSZ + p] = 1.0f/(1.0f + expf(-mx));
}

// K3: 5x5 gaussian smooth (zero pad) + threshold; ego (l==0) mask forced 1.
__global__ __launch_bounds__(256) void k_mask(
    const float* __restrict__ smax, float* __restrict__ mask)
{
    int p = blockIdx.x*256 + threadIdx.x;
    int n = blockIdx.y;
    if (p >= HWSZ) return;
    if ((n % Ll) == 0) { mask[(size_t)n*HWSZ + p] = 1.0f; return; }
    int h = p / WWd, w = p % WWd;
    const float* sm = smax + (size_t)n*HWSZ;
    float c = 0.f;
    #pragma unroll
    for (int dy = -2; dy <= 2; dy++) {
        int hh = h + dy; if (hh < 0 || hh >= HH) continue;
        #pragma unroll
        for (int dx = -2; dx <= 2; dx++) {
            int ww = w + dx; if (ww < 0 || ww >= WWd) continue;
            c += G5[dy+2][dx+2]*sm[hh*WWd + ww];
        }
    }
    mask[(size_t)n*HWSZ + p] = (c > 0.01f) ? 1.0f : 0.0f;
}

// K4: attention fusion, ego row only. float4 over contiguous w.
// Pass 1: dots d_l = <x0, x_l>; logits = 0.125*d_l*mask_l; 5-way softmax.
// Pass 2: out[c] = sum_l (p_l*mask_l) * x_l[c].
__global__ __launch_bounds__(256) void k_fuse(
    const float* __restrict__ x, const float* __restrict__ mask,
    float* __restrict__ out)
{
    int q = blockIdx.x*256 + threadIdx.x;   // float4-pixel index
    int b = blockIdx.y;
    if (q >= HWSZ/4) return;
    int p = q*4;
    const float* xb = x + (size_t)b*Ll*Cc*HWSZ;

    float mk[Ll][4];
    mk[0][0] = mk[0][1] = mk[0][2] = mk[0][3] = 1.0f;
    #pragma unroll
    for (int l = 1; l < Ll; l++) {
        float4 m4 = *(const float4*)(mask + ((size_t)(b*Ll + l))*HWSZ + p);
        mk[l][0] = m4.x; mk[l][1] = m4.y; mk[l][2] = m4.z; mk[l][3] = m4.w;
    }

    float d[Ll][4] = {};
    for (int c = 0; c < Cc; c++) {
        float4 e4 = *(const float4*)(xb + (size_t)c*HWSZ + p);
        float e[4] = {e4.x, e4.y, e4.z, e4.w};
        d[0][0] += e[0]*e[0]; d[0][1] += e[1]*e[1];
        d[0][2] += e[2]*e[2]; d[0][3] += e[3]*e[3];
        #pragma unroll
        for (int l = 1; l < Ll; l++) {
            float4 v4 = *(const float4*)(xb + (size_t)(l*Cc + c)*HWSZ + p);
            d[l][0] += e[0]*v4.x; d[l][1] += e[1]*v4.y;
            d[l][2] += e[2]*v4.z; d[l][3] += e[3]*v4.w;
        }
    }

    float qc[Ll][4];
    #pragma unroll
    for (int j = 0; j < 4; j++) {
        float s[Ll], mx = -1e30f;
        #pragma unroll
        for (int l = 0; l < Ll; l++) {
            s[l] = 0.125f*d[l][j]*mk[l][j];   // masked v_l==0 -> logit 0
            mx = fmaxf(mx, s[l]);
        }
        float sum = 0.f, w[Ll];
        #pragma unroll
        for (int l = 0; l < Ll; l++) { w[l] = expf(s[l] - mx); sum += w[l]; }
        float inv = 1.0f/sum;
        #pragma unroll
        for (int l = 0; l < Ll; l++) qc[l][j] = w[l]*inv*mk[l][j];
    }

    for (int c = 0; c < Cc; c++) {
        float o[4] = {0.f, 0.f, 0.f, 0.f};
        #pragma unroll
        for (int l = 0; l < Ll; l++) {
            float4 v4 = *(const float4*)(xb + (size_t)(l*Cc + c)*HWSZ + p);
            o[0] += qc[l][0]*v4.x; o[1] += qc[l][1]*v4.y;
            o[2] += qc[l][2]*v4.z; o[3] += qc[l][3]*v4.w;
        }
        float4 o4 = make_float4(o[0], o[1], o[2], o[3]);
        *(float4*)(out + ((size_t)b*Cc + c)*HWSZ + p) = o4;
    }
}

extern "C" void kernel_launch(void* const* d_in, const int* in_sizes, int n_in,
                              void* d_out, int out_size, void* d_ws, size_t ws_size,
                              hipStream_t stream) {
    const float* x    = (const float*)d_in[0];   // [20,64,100,352]
    const float* psm  = (const float*)d_in[1];   // [20,2,100,352]
    // d_in[2] record_len (unused), d_in[3] pairwise_t_matrix (unused)
    const float* traj = (const float*)d_in[4];   // [4,5,10,3]
    const float* W1   = (const float*)d_in[5];
    const float* b1   = (const float*)d_in[6];
    const float* W2   = (const float*)d_in[7];
    const float* b2   = (const float*)d_in[8];
    const float* Wc1  = (const float*)d_in[9];
    const float* bc1  = (const float*)d_in[10];
    const float* Wc2  = (const float*)d_in[11];
    const float* bc2  = (const float*)d_in[12];
    float* out = (float*)d_out;

    float* ws      = (float*)d_ws;
    float* tm4     = ws;                       // 20*2200 = 44000
    float* hastraj = ws + 44000;               // 20 (pad to 44032)
    float* smax    = ws + 44032;               // 20*35200 = 704000
    float* maskb   = ws + 44032 + 704000;      // 704000

    k_trajmask<<<dim3(Nn), dim3(256), 0, stream>>>(traj, W1, b1, W2, b2,
                                                   Wc1, bc1, Wc2, bc2, tm4, hastraj);
    k_smax<<<dim3((HWSZ + 255)/256, Nn), dim3(256), 0, stream>>>(psm, tm4, hastraj, smax);
    k_mask<<<dim3((HWSZ + 255)/256, Nn), dim3(256), 0, stream>>>(smax, maskb);
    k_fuse<<<dim3((HWSZ/4 + 255)/256, Bb), dim3(256), 0, stream>>>(x, maskb, out);
}

// Round 2
// 358.263 us; speedup vs baseline: 1.0540x; 1.0540x over previous
//
#include <hip/hip_runtime.h>
#include <math.h>

// Problem constants
#define HH 100
#define WWd 352
#define HWSZ (HH*WWd)      // 35200
#define H4 25
#define W4 88
#define HW4 (H4*W4)        // 2200
#define Bb 4
#define Ll 5
#define Nn 20
#define Cc 64
#define Tt 10

// Fixed 5x5 gaussian (sigma=1), numpy float64 -> float32 path.
__constant__ float G5[5][5] = {
    {(float)0.0029150244650281935, (float)0.0130642332846849210, (float)0.0215392793018486340, (float)0.0130642332846849210, (float)0.0029150244650281935},
    {(float)0.0130642332846849210, (float)0.0585498315243191680, (float)0.0965323526300539140, (float)0.0585498315243191680, (float)0.0130642332846849210},
    {(float)0.0215392793018486340, (float)0.0965323526300539140, (float)0.1591549430918953500, (float)0.0965323526300539140, (float)0.0215392793018486340},
    {(float)0.0130642332846849210, (float)0.0585498315243191680, (float)0.0965323526300539140, (float)0.0585498315243191680, (float)0.0130642332846849210},
    {(float)0.0029150244650281935, (float)0.0130642332846849210, (float)0.0215392793018486340, (float)0.0130642332846849210, (float)0.0029150244650281935},
};

// K1: per-trajectory mask at H4 x W4, plus has_traj flag. One block per n.
// Conv input is spatially constant -> attention map has only 9 distinct
// values (border categories).
__global__ __launch_bounds__(256) void k_trajmask(
    const float* __restrict__ traj,
    const float* __restrict__ W1, const float* __restrict__ b1,
    const float* __restrict__ W2, const float* __restrict__ b2,
    const float* __restrict__ Wc1, const float* __restrict__ bc1,
    const float* __restrict__ Wc2, const float* __restrict__ bc2,
    float* __restrict__ tm4, float* __restrict__ hastraj)
{
    __shared__ float tr[30];
    __shared__ int   xi[10], yi[10];
    __shared__ float hsum[64];
    __shared__ float fmean[128];
    __shared__ float S[576];
    __shared__ float attCat[9];
    __shared__ float mmap[HW4];
    __shared__ float red[256];

    const int n = blockIdx.x, tid = threadIdx.x;
    if (tid < 30) tr[tid] = traj[n*30 + tid];
    __syncthreads();

    if (tid < 10) {
        float px = (tr[tid*3+0] / 0.4f) / 4.0f;
        float py = (tr[tid*3+1] / 0.4f) / 4.0f;
        int x = (int)px; x = min(max(x, 0), W4-1);
        int y = (int)py; y = min(max(y, 0), H4-1);
        xi[tid] = x; yi[tid] = y;
    }
    if (tid == 0) {
        bool any = false;
        for (int i = 0; i < 30; i++) any = any || (tr[i] != 0.0f);
        hastraj[n] = any ? 1.0f : 0.0f;
    }
    if (tid < 64) {
        float s = 0.f;
        for (int t = 0; t < 10; t++) {
            float h = tr[t*3+0]*W1[tid] + tr[t*3+1]*W1[64+tid] + tr[t*3+2]*W1[128+tid] + b1[tid];
            s += fmaxf(h, 0.f);
        }
        hsum[tid] = s;
    }
    __syncthreads();

    if (tid < 128) {
        float s = 0.f;
        for (int j = 0; j < 64; j++) s += hsum[j]*W2[j*128 + tid];
        fmean[tid] = s/10.0f + b2[tid];
    }
    __syncthreads();

    for (int idx = tid; idx < 576; idx += 256) {
        int o = idx/9, kk = idx%9;
        const float* w = Wc1 + o*128*9 + kk;
        float s = 0.f;
        for (int ci = 0; ci < 128; ci++) s += w[ci*9]*fmean[ci];
        S[idx] = s;
    }
    __syncthreads();

    if (tid < 9) {
        int ty = tid/3, tx = tid%3;
        int kh0 = (ty==0)?1:0, kh1 = (ty==2)?1:2;
        int kw0 = (tx==0)?1:0, kw1 = (tx==2)?1:2;
        float acc = bc2[0];
        for (int o = 0; o < 64; o++) {
            float s = bc1[o];
            for (int kh = kh0; kh <= kh1; kh++)
                for (int kw = kw0; kw <= kw1; kw++)
                    s += S[o*9 + kh*3 + kw];
            acc += Wc2[o]*fmaxf(s, 0.f);
        }
        attCat[tid] = 1.0f/(1.0f + expf(-acc));
    }

    float part = 0.f;
    for (int p = tid; p < HW4; p += 256) {
        int y = p/W4, x = p%W4;
        float m = 0.f;
        for (int t = 0; t < 10; t++) {
            int dy = y - yi[t], dx = x - xi[t];
            if (dy >= -3 && dy <= 3 && dx >= -3 && dx <= 3)
                m += expf(-(float)(dy*dy + dx*dx)*0.125f);
        }
        mmap[p] = m; part += m;
    }
    red[tid] = part;
    __syncthreads();
    for (int s = 128; s > 0; s >>= 1) {
        if (tid < s) red[tid] += red[tid+s];
        __syncthreads();
    }
    float norm = fmaxf(red[0], 1e-12f);

    for (int p = tid; p < HW4; p += 256) {
        int y = p/W4, x = p%W4;
        int ty = (y==0)?0:((y==H4-1)?2:1);
        int tx = (x==0)?0:((x==W4-1)?2:1);
        tm4[n*HW4 + p] = (mmap[p]/norm)*attCat[ty*3 + tx];
    }
}

// K2: smax[n,h,w] = sigmoid(max_a(psm[n,a,h,w] * (1 + has_traj*tm_up)))
__global__ __launch_bounds__(256) void k_smax(
    const float* __restrict__ psm, const float* __restrict__ tm4,
    const float* __restrict__ hastraj, float* __restrict__ smax)
{
    int p = blockIdx.x*256 + threadIdx.x;
    int n = blockIdx.y;
    if (p >= HWSZ) return;
    int h = p / WWd, w = p % WWd;

    float fy = (h + 0.5f)*0.25f - 0.5f;
    float fx = (w + 0.5f)*0.25f - 0.5f;
    int y0 = (int)floorf(fy); float fry = fy - (float)y0;
    int x0 = (int)floorf(fx); float frx = fx - (float)x0;
    int ya = min(max(y0, 0), H4-1), yb = min(max(y0+1, 0), H4-1);
    int xa = min(max(x0, 0), W4-1), xb = min(max(x0+1, 0), W4-1);
    const float* tm = tm4 + n*HW4;
    float v00 = tm[ya*W4+xa], v01 = tm[ya*W4+xb];
    float v10 = tm[yb*W4+xa], v11 = tm[yb*W4+xb];
    float top = (1.f-frx)*v00 + frx*v01;
    float bot = (1.f-frx)*v10 + frx*v11;
    float tmv = (1.f-fry)*top + fry*bot;

    float fac = 1.0f + hastraj[n]*tmv;
    float a0 = psm[(size_t)(n*2+0)*HWSZ + p]*fac;
    float a1 = psm[(size_t)(n*2+1)*HWSZ + p]*fac;
    float mx = fmaxf(a0, a1);
    smax[(size_t)n*HWSZ + p] = 1.0f/(1.0f + expf(-mx));
}

// K3: 5x5 gaussian smooth (zero pad) + threshold; ego (l==0) mask forced 1.
__global__ __launch_bounds__(256) void k_mask(
    const float* __restrict__ smax, float* __restrict__ mask)
{
    int p = blockIdx.x*256 + threadIdx.x;
    int n = blockIdx.y;
    if (p >= HWSZ) return;
    if ((n % Ll) == 0) { mask[(size_t)n*HWSZ + p] = 1.0f; return; }
    int h = p / WWd, w = p % WWd;
    const float* sm = smax + (size_t)n*HWSZ;
    float c = 0.f;
    #pragma unroll
    for (int dy = -2; dy <= 2; dy++) {
        int hh = h + dy; if (hh < 0 || hh >= HH) continue;
        #pragma unroll
        for (int dx = -2; dx <= 2; dx++) {
            int ww = w + dx; if (ww < 0 || ww >= WWd) continue;
            c += G5[dy+2][dx+2]*sm[hh*WWd + ww];
        }
    }
    mask[(size_t)n*HWSZ + p] = (c > 0.01f) ? 1.0f : 0.0f;
}

// K4: attention fusion, ego row only. Single pass over x.
// Block = 64 pixels x 4 channel-chunks (16 ch each). Each thread register-
// caches x[l][chunk-channels][pixel], computes partial dots, LDS-reduces
// across chunks, chunk-0 wave does the 5-way softmax, all threads emit out
// from register-cached x. x is read exactly once from HBM.
__global__ __launch_bounds__(256) void k_fuse(
    const float* __restrict__ x, const float* __restrict__ mask,
    float* __restrict__ out)
{
    __shared__ float dred[4][64][Ll];   // [chunk][pix][l]
    __shared__ float qsh[64][Ll];       // folded softmax*mask weights

    const int tid   = threadIdx.x;
    const int pix   = tid & 63;
    const int chunk = tid >> 6;         // 0..3 -> channels chunk*16..+15
    const int p     = blockIdx.x*64 + pix;
    const int b     = blockIdx.y;

    // per-pixel masks (ego forced 1)
    float mk[Ll];
    mk[0] = 1.0f;
    #pragma unroll
    for (int l = 1; l < Ll; l++)
        mk[l] = mask[((size_t)(b*Ll + l))*HWSZ + p];

    // register-cache x: 5 agents x 16 channels
    float xr[Ll][16];
    const float* xb = x + (size_t)b*Ll*Cc*HWSZ + (size_t)chunk*16*HWSZ + p;
    #pragma unroll
    for (int l = 0; l < Ll; l++) {
        const float* xl = xb + (size_t)l*Cc*HWSZ;
        #pragma unroll
        for (int k = 0; k < 16; k++)
            xr[l][k] = xl[(size_t)k*HWSZ];
    }

    // partial dots over this chunk's channels
    #pragma unroll
    for (int l = 0; l < Ll; l++) {
        float s = 0.f;
        #pragma unroll
        for (int k = 0; k < 16; k++) s += xr[0][k]*xr[l][k];
        dred[chunk][pix][l] = s;
    }
    __syncthreads();

    if (tid < 64) {
        float sl[Ll], mx = -1e30f;
        #pragma unroll
        for (int l = 0; l < Ll; l++) {
            float d = dred[0][tid][l] + dred[1][tid][l] + dred[2][tid][l] + dred[3][tid][l];
            sl[l] = 0.125f * d * mk[l];   // masked v -> logit 0
            mx = fmaxf(mx, sl[l]);
        }
        float sum = 0.f, w[Ll];
        #pragma unroll
        for (int l = 0; l < Ll; l++) { w[l] = expf(sl[l] - mx); sum += w[l]; }
        float inv = 1.0f/sum;
        #pragma unroll
        for (int l = 0; l < Ll; l++) qsh[tid][l] = w[l]*inv*mk[l];
    }
    __syncthreads();

    float q[Ll];
    #pragma unroll
    for (int l = 0; l < Ll; l++) q[l] = qsh[pix][l];

    float* ob = out + ((size_t)b*Cc + chunk*16)*HWSZ + p;
    #pragma unroll
    for (int k = 0; k < 16; k++) {
        float o = 0.f;
        #pragma unroll
        for (int l = 0; l < Ll; l++) o += q[l]*xr[l][k];
        ob[(size_t)k*HWSZ] = o;
    }
}

extern "C" void kernel_launch(void* const* d_in, const int* in_sizes, int n_in,
                              void* d_out, int out_size, void* d_ws, size_t ws_size,
                              hipStream_t stream) {
    const float* x    = (const float*)d_in[0];
    const float* psm  = (const float*)d_in[1];
    const float* traj = (const float*)d_in[4];
    const float* W1   = (const float*)d_in[5];
    const float* b1   = (const float*)d_in[6];
    const float* W2   = (const float*)d_in[7];
    const float* b2   = (const float*)d_in[8];
    const float* Wc1  = (const float*)d_in[9];
    const float* bc1  = (const float*)d_in[10];
    const float* Wc2  = (const float*)d_in[11];
    const float* bc2  = (const float*)d_in[12];
    float* out = (float*)d_out;

    float* ws      = (float*)d_ws;
    float* tm4     = ws;                       // 20*2200 = 44000
    float* hastraj = ws + 44000;               // 20 (pad to 44032)
    float* smax    = ws + 44032;               // 20*35200 = 704000
    float* maskb   = ws + 44032 + 704000;      // 704000

    k_trajmask<<<dim3(Nn), dim3(256), 0, stream>>>(traj, W1, b1, W2, b2,
                                                   Wc1, bc1, Wc2, bc2, tm4, hastraj);
    k_smax<<<dim3((HWSZ + 255)/256, Nn), dim3(256), 0, stream>>>(psm, tm4, hastraj, smax);
    k_mask<<<dim3((HWSZ + 255)/256, Nn), dim3(256), 0, stream>>>(smax, maskb);
    k_fuse<<<dim3(HWSZ/64, Bb), dim3(256), 0, stream>>>(x, maskb, out);
}

// Round 3
// 355.140 us; speedup vs baseline: 1.0632x; 1.0088x over previous
//
#include <hip/hip_runtime.h>
#include <math.h>

// Problem constants
#define HH 100
#define WWd 352
#define HWSZ (HH*WWd)      // 35200
#define H4 25
#define W4 88
#define HW4 (H4*W4)        // 2200
#define Bb 4
#define Ll 5
#define Nn 20
#define Cc 64
#define Tt 10

// Fixed 5x5 gaussian (sigma=1), numpy float64 -> float32 path.
__constant__ float G5[5][5] = {
    {(float)0.0029150244650281935, (float)0.0130642332846849210, (float)0.0215392793018486340, (float)0.0130642332846849210, (float)0.0029150244650281935},
    {(float)0.0130642332846849210, (float)0.0585498315243191680, (float)0.0965323526300539140, (float)0.0585498315243191680, (float)0.0130642332846849210},
    {(float)0.0215392793018486340, (float)0.0965323526300539140, (float)0.1591549430918953500, (float)0.0965323526300539140, (float)0.0215392793018486340},
    {(float)0.0130642332846849210, (float)0.0585498315243191680, (float)0.0965323526300539140, (float)0.0585498315243191680, (float)0.0130642332846849210},
    {(float)0.0029150244650281935, (float)0.0130642332846849210, (float)0.0215392793018486340, (float)0.0130642332846849210, (float)0.0029150244650281935},
};

// K1: per-trajectory mask at H4 x W4, plus has_traj flag. One block per n.
// Conv input is spatially constant -> attention map has only 9 distinct
// values (border categories).
__global__ __launch_bounds__(256) void k_trajmask(
    const float* __restrict__ traj,
    const float* __restrict__ W1, const float* __restrict__ b1,
    const float* __restrict__ W2, const float* __restrict__ b2,
    const float* __restrict__ Wc1, const float* __restrict__ bc1,
    const float* __restrict__ Wc2, const float* __restrict__ bc2,
    float* __restrict__ tm4, float* __restrict__ hastraj)
{
    __shared__ float tr[30];
    __shared__ int   xi[10], yi[10];
    __shared__ float hsum[64];
    __shared__ float fmean[128];
    __shared__ float S[576];
    __shared__ float attCat[9];
    __shared__ float mmap[HW4];
    __shared__ float red[256];

    const int n = blockIdx.x, tid = threadIdx.x;
    if (tid < 30) tr[tid] = traj[n*30 + tid];
    __syncthreads();

    if (tid < 10) {
        float px = (tr[tid*3+0] / 0.4f) / 4.0f;
        float py = (tr[tid*3+1] / 0.4f) / 4.0f;
        int x = (int)px; x = min(max(x, 0), W4-1);
        int y = (int)py; y = min(max(y, 0), H4-1);
        xi[tid] = x; yi[tid] = y;
    }
    if (tid == 0) {
        bool any = false;
        for (int i = 0; i < 30; i++) any = any || (tr[i] != 0.0f);
        hastraj[n] = any ? 1.0f : 0.0f;
    }
    if (tid < 64) {
        float s = 0.f;
        for (int t = 0; t < 10; t++) {
            float h = tr[t*3+0]*W1[tid] + tr[t*3+1]*W1[64+tid] + tr[t*3+2]*W1[128+tid] + b1[tid];
            s += fmaxf(h, 0.f);
        }
        hsum[tid] = s;
    }
    __syncthreads();

    if (tid < 128) {
        float s = 0.f;
        for (int j = 0; j < 64; j++) s += hsum[j]*W2[j*128 + tid];
        fmean[tid] = s/10.0f + b2[tid];
    }
    __syncthreads();

    for (int idx = tid; idx < 576; idx += 256) {
        int o = idx/9, kk = idx%9;
        const float* w = Wc1 + o*128*9 + kk;
        float s = 0.f;
        for (int ci = 0; ci < 128; ci++) s += w[ci*9]*fmean[ci];
        S[idx] = s;
    }
    __syncthreads();

    if (tid < 9) {
        int ty = tid/3, tx = tid%3;
        int kh0 = (ty==0)?1:0, kh1 = (ty==2)?1:2;
        int kw0 = (tx==0)?1:0, kw1 = (tx==2)?1:2;
        float acc = bc2[0];
        for (int o = 0; o < 64; o++) {
            float s = bc1[o];
            for (int kh = kh0; kh <= kh1; kh++)
                for (int kw = kw0; kw <= kw1; kw++)
                    s += S[o*9 + kh*3 + kw];
            acc += Wc2[o]*fmaxf(s, 0.f);
        }
        attCat[tid] = 1.0f/(1.0f + expf(-acc));
    }

    float part = 0.f;
    for (int p = tid; p < HW4; p += 256) {
        int y = p/W4, x = p%W4;
        float m = 0.f;
        for (int t = 0; t < 10; t++) {
            int dy = y - yi[t], dx = x - xi[t];
            if (dy >= -3 && dy <= 3 && dx >= -3 && dx <= 3)
                m += expf(-(float)(dy*dy + dx*dx)*0.125f);
        }
        mmap[p] = m; part += m;
    }
    red[tid] = part;
    __syncthreads();
    for (int s = 128; s > 0; s >>= 1) {
        if (tid < s) red[tid] += red[tid+s];
        __syncthreads();
    }
    float norm = fmaxf(red[0], 1e-12f);

    for (int p = tid; p < HW4; p += 256) {
        int y = p/W4, x = p%W4;
        int ty = (y==0)?0:((y==H4-1)?2:1);
        int tx = (x==0)?0:((x==W4-1)?2:1);
        tm4[n*HW4 + p] = (mmap[p]/norm)*attCat[ty*3 + tx];
    }
}

// K2 (fused smax + 5x5 gaussian + threshold): mask for NON-EGO agents only
// (k_fuse hardcodes ego mask = 1, so ego rows are never read).
// Tile = 8 output rows x full width; smax computed into LDS with 2-halo on
// all sides (zero-padded), then 5x5 conv + threshold.
__global__ __launch_bounds__(256) void k_commmask(
    const float* __restrict__ psm, const float* __restrict__ tm4,
    const float* __restrict__ hastraj, float* __restrict__ mask)
{
    __shared__ float sm[12][WWd + 4];   // rows h0-2..h0+9, cols -2..353

    const int tid = threadIdx.x;
    const int yb  = blockIdx.y;                      // 0..15 -> non-ego n
    const int n   = (yb >> 2)*Ll + 1 + (yb & 3);
    const int h0  = blockIdx.x * 8;

    // zero the side halo columns
    if (tid < 24) {
        int r = tid >> 1, c = tid & 1;
        sm[r][c] = 0.f;
        sm[r][WWd + 2 + c] = 0.f;
    }

    const float ht = hastraj[n];
    const float* tm = tm4 + n*HW4;
    const float* ps0 = psm + (size_t)(n*2 + 0)*HWSZ;
    const float* ps1 = psm + (size_t)(n*2 + 1)*HWSZ;

    // compute smax for the 12 halo rows (zero outside image)
    for (int idx = tid; idx < 12*WWd; idx += 256) {
        int r = idx / WWd, w = idx % WWd;
        int h = h0 - 2 + r;
        float v = 0.f;
        if (h >= 0 && h < HH) {
            // bilinear x4 upsample of tm4 (half-pixel, edge-clamped)
            float fy = (h + 0.5f)*0.25f - 0.5f;
            float fx = (w + 0.5f)*0.25f - 0.5f;
            int y0 = (int)floorf(fy); float fry = fy - (float)y0;
            int x0 = (int)floorf(fx); float frx = fx - (float)x0;
            int ya = min(max(y0, 0), H4-1), yc = min(max(y0+1, 0), H4-1);
            int xa = min(max(x0, 0), W4-1), xc = min(max(x0+1, 0), W4-1);
            float v00 = tm[ya*W4+xa], v01 = tm[ya*W4+xc];
            float v10 = tm[yc*W4+xa], v11 = tm[yc*W4+xc];
            float top = (1.f-frx)*v00 + frx*v01;
            float bot = (1.f-frx)*v10 + frx*v11;
            float tmv = (1.f-fry)*top + fry*bot;

            float fac = 1.0f + ht*tmv;
            int p = h*WWd + w;
            float mx = fmaxf(ps0[p]*fac, ps1[p]*fac);   // max(sig(a),sig(b))=sig(max)
            v = 1.0f/(1.0f + expf(-mx));
        }
        sm[r][w + 2] = v;
    }
    __syncthreads();

    // 5x5 conv + threshold on the 8 valid rows
    for (int idx = tid; idx < 8*WWd; idx += 256) {
        int r = idx / WWd, w = idx % WWd;
        int h = h0 + r;
        if (h >= HH) continue;
        float c = 0.f;
        #pragma unroll
        for (int dy = 0; dy < 5; dy++) {
            #pragma unroll
            for (int dx = 0; dx < 5; dx++)
                c += G5[dy][dx]*sm[r + dy][w + dx];
        }
        mask[(size_t)n*HWSZ + h*WWd + w] = (c > 0.01f) ? 1.0f : 0.0f;
    }
}

// K3: attention fusion, ego row only. Single pass over x.
// Block = 64 pixels x 4 channel-chunks (16 ch each). Each thread register-
// caches x[l][chunk-channels][pixel], computes partial dots, LDS-reduces
// across chunks, chunk-0 wave does the 5-way softmax, all threads emit out
// from register-cached x. x is read exactly once from HBM.
__global__ __launch_bounds__(256) void k_fuse(
    const float* __restrict__ x, const float* __restrict__ mask,
    float* __restrict__ out)
{
    __shared__ float dred[4][64][Ll];   // [chunk][pix][l]
    __shared__ float qsh[64][Ll];       // folded softmax*mask weights

    const int tid   = threadIdx.x;
    const int pix   = tid & 63;
    const int chunk = tid >> 6;         // 0..3 -> channels chunk*16..+15
    const int p     = blockIdx.x*64 + pix;
    const int b     = blockIdx.y;

    float mk[Ll];
    mk[0] = 1.0f;
    #pragma unroll
    for (int l = 1; l < Ll; l++)
        mk[l] = mask[((size_t)(b*Ll + l))*HWSZ + p];

    float xr[Ll][16];
    const float* xb = x + (size_t)b*Ll*Cc*HWSZ + (size_t)chunk*16*HWSZ + p;
    #pragma unroll
    for (int l = 0; l < Ll; l++) {
        const float* xl = xb + (size_t)l*Cc*HWSZ;
        #pragma unroll
        for (int k = 0; k < 16; k++)
            xr[l][k] = xl[(size_t)k*HWSZ];
    }

    #pragma unroll
    for (int l = 0; l < Ll; l++) {
        float s = 0.f;
        #pragma unroll
        for (int k = 0; k < 16; k++) s += xr[0][k]*xr[l][k];
        dred[chunk][pix][l] = s;
    }
    __syncthreads();

    if (tid < 64) {
        float sl[Ll], mx = -1e30f;
        #pragma unroll
        for (int l = 0; l < Ll; l++) {
            float d = dred[0][tid][l] + dred[1][tid][l] + dred[2][tid][l] + dred[3][tid][l];
            sl[l] = 0.125f * d * mk[l];   // masked v -> logit 0
            mx = fmaxf(mx, sl[l]);
        }
        float sum = 0.f, w[Ll];
        #pragma unroll
        for (int l = 0; l < Ll; l++) { w[l] = expf(sl[l] - mx); sum += w[l]; }
        float inv = 1.0f/sum;
        #pragma unroll
        for (int l = 0; l < Ll; l++) qsh[tid][l] = w[l]*inv*mk[l];
    }
    __syncthreads();

    float q[Ll];
    #pragma unroll
    for (int l = 0; l < Ll; l++) q[l] = qsh[pix][l];

    float* ob = out + ((size_t)b*Cc + chunk*16)*HWSZ + p;
    #pragma unroll
    for (int k = 0; k < 16; k++) {
        float o = 0.f;
        #pragma unroll
        for (int l = 0; l < Ll; l++) o += q[l]*xr[l][k];
        ob[(size_t)k*HWSZ] = o;
    }
}

extern "C" void kernel_launch(void* const* d_in, const int* in_sizes, int n_in,
                              void* d_out, int out_size, void* d_ws, size_t ws_size,
                              hipStream_t stream) {
    const float* x    = (const float*)d_in[0];
    const float* psm  = (const float*)d_in[1];
    const float* traj = (const float*)d_in[4];
    const float* W1   = (const float*)d_in[5];
    const float* b1   = (const float*)d_in[6];
    const float* W2   = (const float*)d_in[7];
    const float* b2   = (const float*)d_in[8];
    const float* Wc1  = (const float*)d_in[9];
    const float* bc1  = (const float*)d_in[10];
    const float* Wc2  = (const float*)d_in[11];
    const float* bc2  = (const float*)d_in[12];
    float* out = (float*)d_out;

    float* ws      = (float*)d_ws;
    float* tm4     = ws;                       // 20*2200 = 44000
    float* hastraj = ws + 44000;               // 20 (pad to 44032)
    float* maskb   = ws + 44032;               // 20*35200 (ego slots unwritten/unread)

    k_trajmask<<<dim3(Nn), dim3(256), 0, stream>>>(traj, W1, b1, W2, b2,
                                                   Wc1, bc1, Wc2, bc2, tm4, hastraj);
    k_commmask<<<dim3((HH + 7)/8, 16), dim3(256), 0, stream>>>(psm, tm4, hastraj, maskb);
    k_fuse<<<dim3(HWSZ/64, Bb), dim3(256), 0, stream>>>(x, maskb, out);
}